// Round 1
// 375.099 us; speedup vs baseline: 1.0508x; 1.0508x over previous
//
#include <hip/hip_runtime.h>

// RGCN layer, MI355X. Round 8:
//   ws: Cp[N][512] bf16 (C0|C1), Xbf[N][256] bf16, Bfrag[6][8][8][64][8] bf16,
//       rec[N][16] int (cnt + 15 edges, ONE 64B line per dst), ovf[N][16] int
//   K1 prep:  fused { edge bucketing FIRST (overlaps under streaming),
//                     Bfrag build, conv_x -> Xbf }
//             bucketing: atomic + store hit the SAME 64B line (rec layout)
//   K2 agg:   2 dsts per wave; rec line read coalesced (lane0=cnt, lanes1..15
//             edges, lanes16..31 overflow); bf16 uint4/lane gathers
//   K3 gemm:  128x256 tile, BK=32, A+B double-buffered LDS via global_load_lds,
//             fused bias+LayerNorm+ReLU (unchanged)

#define NN 100000
#define NR 4
#define NE 200000
#define BM 128

typedef __attribute__((ext_vector_type(8))) short short8;
typedef __attribute__((ext_vector_type(16))) float floatx16;

__device__ __forceinline__ unsigned short f2bf(float f) {
  unsigned u = __float_as_uint(f);
  u += 0x7FFFu + ((u >> 16) & 1u);
  return (unsigned short)(u >> 16);
}

__device__ __forceinline__ void gload16(const unsigned short* g, unsigned short* l) {
  __builtin_amdgcn_global_load_lds(
      (const __attribute__((address_space(1))) unsigned int*)g,
      (__attribute__((address_space(3))) unsigned int*)l, 16, 0, 0);
}

// ---------------- K1: fused prep ----------------
__global__ void prep(const float* __restrict__ x, const float* __restrict__ bases,
                     const float* __restrict__ loop_w, const int* __restrict__ src,
                     const int* __restrict__ dst, unsigned short* __restrict__ Xbf,
                     unsigned short* __restrict__ Bfrag, int* __restrict__ rec,
                     int* __restrict__ ovf) {
  const int b = blockIdx.x;
  const int tid = threadIdx.x;
  if (b < 3125) {
    // edge bucketing: one atomic per edge; store lands in the SAME 64B line
    int i = b * 256 + tid;  // 3125*256 = 800000 exact
    int r = i / NE;
    int s = src[i];
    int dd = dst[i];
    int pos = atomicAdd(&rec[dd * 16], 1);
    int v = s | (r << 20);  // src<2^17, rel bits 20-21
    if (pos < 15) rec[dd * 16 + 1 + pos] = v;
    else if (pos < 31) ovf[dd * 16 + (pos - 15)] = v;
  } else if (b < 3893) {
    // Bfrag: fragment-major B. idx = ((s*8+j)*8+t)*512 + lane*8 + e
    // maps to n = t*32+(lane&31), k = s*128 + j*16 + (lane>>5)*8 + e
    int i = (b - 3125) * 256 + tid;  // 196608 exact
    int e = i & 7;
    int lane = (i >> 3) & 63;
    int f = i >> 9;
    int t = f & 7;
    int j = (f >> 3) & 7;
    int s = f >> 6;
    int n = t * 32 + (lane & 31);
    int k = s * 128 + j * 16 + (lane >> 5) * 8 + e;
    float v;
    if (k < 256)      v = bases[k * 256 + n];
    else if (k < 512) v = bases[65536 + (k - 256) * 256 + n];
    else              v = loop_w[(k - 512) * 256 + n];
    Bfrag[i] = f2bf(v);
  } else {
    // conv_x: x fp32 -> bf16 compact panel; 8 cols per thread
    int i = (b - 3893) * 256 + tid;  // 3.2M threads exact
    int row = i >> 5;
    int col = (i & 31) << 3;
    const float4 v0 = *(const float4*)(x + (size_t)row * 256 + col);
    const float4 v1 = *(const float4*)(x + (size_t)row * 256 + col + 4);
    uint4 u;
    u.x = (unsigned)f2bf(v0.x) | ((unsigned)f2bf(v0.y) << 16);
    u.y = (unsigned)f2bf(v0.z) | ((unsigned)f2bf(v0.w) << 16);
    u.z = (unsigned)f2bf(v1.x) | ((unsigned)f2bf(v1.y) << 16);
    u.w = (unsigned)f2bf(v1.z) | ((unsigned)f2bf(v1.w) << 16);
    *(uint4*)(Xbf + (size_t)row * 256 + col) = u;
  }
}

// ---------------- K2: aggregation, 2 dsts per wave, bf16 16B/lane gathers ----------------
__global__ void agg_edges(const int* __restrict__ rec, const int* __restrict__ ovf,
                          const float* __restrict__ w_comp,
                          const unsigned short* __restrict__ Xbf,
                          unsigned short* __restrict__ Cp) {
  const int tid = threadIdx.x;
  const int lane = tid & 63;
  const int wave = tid >> 6;
  const int half = lane >> 5;
  const int l31 = lane & 31;
  const int d = blockIdx.x * 8 + wave * 2 + half;  // 12500*8 = 100000 exact
  const int selbase = lane & 32;

  // one 64B line per dst: [0]=cnt, [1..15]=edges; lanes 16..31 fetch overflow
  int raw = 0;
  if (l31 < 16) raw = rec[d * 16 + l31];
  int cc = __shfl(raw, selbase);  // element 0 of this half's line
  cc = cc < 31 ? cc : 31;
  int ev = 0;
  const bool val = (l31 >= 1) && (l31 <= cc);
  if (val) {
    if (l31 < 16) ev = raw;                      // edge (l31-1)
    else ev = ovf[d * 16 + (l31 - 16)];          // edge (l31-1) = 15 + (l31-16)
  }
  const int rl = (ev >> 20) & 3;

  unsigned long long b0 = __ballot(val && rl == 0);
  unsigned long long b1 = __ballot(val && rl == 1);
  unsigned long long b2 = __ballot(val && rl == 2);
  unsigned long long b3 = __ballot(val && rl == 3);
  const int sh = half << 5;
  float i0 = 1.0f / fmaxf((float)__popc((unsigned)(b0 >> sh)), 1.0f);
  float i1 = 1.0f / fmaxf((float)__popc((unsigned)(b1 >> sh)), 1.0f);
  float i2 = 1.0f / fmaxf((float)__popc((unsigned)(b2 >> sh)), 1.0f);
  float i3 = 1.0f / fmaxf((float)__popc((unsigned)(b3 >> sh)), 1.0f);
  float s00 = w_comp[0] * i0, s10 = w_comp[1] * i0;
  float s01 = w_comp[2] * i1, s11 = w_comp[3] * i1;
  float s02 = w_comp[4] * i2, s12 = w_comp[5] * i2;
  float s03 = w_comp[6] * i3, s13 = w_comp[7] * i3;

  float a0[8] = {0.f, 0.f, 0.f, 0.f, 0.f, 0.f, 0.f, 0.f};
  float a1[8] = {0.f, 0.f, 0.f, 0.f, 0.f, 0.f, 0.f, 0.f};
  const unsigned short* Xp = Xbf + l31 * 8;

#define EDGE_W(v, w0, w1)                                            \
  int r_##w0 = ((v) >> 20) & 3;                                      \
  float w0 = r_##w0 < 2 ? (r_##w0 == 0 ? s00 : s01)                  \
                        : (r_##w0 == 2 ? s02 : s03);                 \
  float w1 = r_##w0 < 2 ? (r_##w0 == 0 ? s10 : s11)                  \
                        : (r_##w0 == 2 ? s12 : s13);

#define ACC8(g, w0, w1)                                              \
  {                                                                  \
    float e0 = __uint_as_float((g).x << 16);                         \
    float e1 = __uint_as_float((g).x & 0xFFFF0000u);                 \
    float e2 = __uint_as_float((g).y << 16);                         \
    float e3 = __uint_as_float((g).y & 0xFFFF0000u);                 \
    float e4 = __uint_as_float((g).z << 16);                         \
    float e5 = __uint_as_float((g).z & 0xFFFF0000u);                 \
    float e6 = __uint_as_float((g).w << 16);                         \
    float e7 = __uint_as_float((g).w & 0xFFFF0000u);                 \
    a0[0] += (w0) * e0; a0[1] += (w0) * e1; a0[2] += (w0) * e2;      \
    a0[3] += (w0) * e3; a0[4] += (w0) * e4; a0[5] += (w0) * e5;      \
    a0[6] += (w0) * e6; a0[7] += (w0) * e7;                          \
    a1[0] += (w1) * e0; a1[1] += (w1) * e1; a1[2] += (w1) * e2;      \
    a1[3] += (w1) * e3; a1[4] += (w1) * e4; a1[5] += (w1) * e5;      \
    a1[6] += (w1) * e6; a1[7] += (w1) * e7;                          \
  }

  int i = 0;
  for (; i + 4 <= cc; i += 4) {
    int v0 = __shfl(ev, selbase + 1 + i);
    int v1 = __shfl(ev, selbase + 2 + i);
    int v2 = __shfl(ev, selbase + 3 + i);
    int v3 = __shfl(ev, selbase + 4 + i);
    const uint4 g0 = *(const uint4*)(Xp + (size_t)(v0 & 0xFFFFF) * 256);
    const uint4 g1 = *(const uint4*)(Xp + (size_t)(v1 & 0xFFFFF) * 256);
    const uint4 g2 = *(const uint4*)(Xp + (size_t)(v2 & 0xFFFFF) * 256);
    const uint4 g3 = *(const uint4*)(Xp + (size_t)(v3 & 0xFFFFF) * 256);
    { EDGE_W(v0, w0a, w1a) ACC8(g0, w0a, w1a) }
    { EDGE_W(v1, w0b, w1b) ACC8(g1, w0b, w1b) }
    { EDGE_W(v2, w0c, w1c) ACC8(g2, w0c, w1c) }
    { EDGE_W(v3, w0d, w1d) ACC8(g3, w0d, w1d) }
  }
  for (; i < cc; ++i) {
    int v = __shfl(ev, selbase + 1 + i);
    const uint4 g = *(const uint4*)(Xp + (size_t)(v & 0xFFFFF) * 256);
    EDGE_W(v, w0, w1)
    ACC8(g, w0, w1)
  }

  uint4 o0, o1;
  o0.x = (unsigned)f2bf(a0[0]) | ((unsigned)f2bf(a0[1]) << 16);
  o0.y = (unsigned)f2bf(a0[2]) | ((unsigned)f2bf(a0[3]) << 16);
  o0.z = (unsigned)f2bf(a0[4]) | ((unsigned)f2bf(a0[5]) << 16);
  o0.w = (unsigned)f2bf(a0[6]) | ((unsigned)f2bf(a0[7]) << 16);
  o1.x = (unsigned)f2bf(a1[0]) | ((unsigned)f2bf(a1[1]) << 16);
  o1.y = (unsigned)f2bf(a1[2]) | ((unsigned)f2bf(a1[3]) << 16);
  o1.z = (unsigned)f2bf(a1[4]) | ((unsigned)f2bf(a1[5]) << 16);
  o1.w = (unsigned)f2bf(a1[6]) | ((unsigned)f2bf(a1[7]) << 16);
  *(uint4*)(Cp + (size_t)d * 512 + l31 * 8) = o0;
  *(uint4*)(Cp + (size_t)d * 512 + 256 + l31 * 8) = o1;
}

// ---------------- K3: GEMM + bias + LN + ReLU (vmcnt-pipelined LDS dbuf) ----------------
__launch_bounds__(256, 2)
__global__ void gemm_ln(const unsigned short* __restrict__ Cp,
                        const unsigned short* __restrict__ Xbf,
                        const unsigned short* __restrict__ Bfrag,
                        const float* __restrict__ h_bias, const float* __restrict__ gamma,
                        const float* __restrict__ beta, float* __restrict__ out) {
  __shared__ unsigned short Ab[2][128 * 32];  // 16 KB
  __shared__ unsigned short Bb[2][256 * 32];  // 32 KB
  const int tid = threadIdx.x;
  const int wave = tid >> 6;
  const int lane = tid & 63;
  const int l31 = lane & 31;
  const int half = lane >> 5;
  const int m0 = blockIdx.x * BM;

  floatx16 acc[8];
#pragma unroll
  for (int t = 0; t < 8; ++t)
#pragma unroll
    for (int r = 0; r < 16; ++r) acc[t][r] = 0.0f;

  int arow = m0 + 32 * wave + l31;
  if (arow >= NN) arow = NN - 1;  // dup tail rows; outputs guarded
  const unsigned short* pC0 = Cp + (size_t)arow * 512 + half * 8;
  const unsigned short* pC1 = pC0 + 16;
  const unsigned short* pX0 = Xbf + (size_t)arow * 256 + half * 8;
  const unsigned short* pX1 = pX0 + 16;
  const unsigned short* pB = Bfrag + tid * 8;

#define STAGE(s, buf)                                                     \
  {                                                                       \
    const int ks = (s) * 32;                                              \
    const unsigned short* a0 = ((s) < 16) ? pC0 + ks : pX0 + ks - 512;    \
    const unsigned short* a1 = ((s) < 16) ? pC1 + ks : pX1 + ks - 512;    \
    gload16(a0, &Ab[buf][(wave * 2 + 0) * 64 * 8] + lane * 8);            \
    gload16(a1, &Ab[buf][(wave * 2 + 1) * 64 * 8] + lane * 8);            \
    const unsigned short* bsrc = pB + (size_t)(s) * 8192;                 \
    gload16(bsrc,        &Bb[buf][0]    + tid * 8);                       \
    gload16(bsrc + 2048, &Bb[buf][2048] + tid * 8);                       \
    gload16(bsrc + 4096, &Bb[buf][4096] + tid * 8);                       \
    gload16(bsrc + 6144, &Bb[buf][6144] + tid * 8);                       \
  }

  STAGE(0, 0)
  __syncthreads();

  for (int s = 0; s < 24; ++s) {
    const int cur = s & 1;
    if (s < 23) STAGE(s + 1, cur ^ 1)
#pragma unroll
    for (int j = 0; j < 2; ++j) {
      short8 af = *(const short8*)(&Ab[cur][(wave * 2 + j) * 512] + lane * 8);
#pragma unroll
      for (int t = 0; t < 8; ++t) {
        short8 bfr = *(const short8*)(&Bb[cur][(j * 8 + t) * 512] + lane * 8);
        acc[t] = __builtin_amdgcn_mfma_f32_32x32x16_bf16(af, bfr, acc[t], 0, 0, 0);
      }
    }
    __syncthreads();
  }

  // epilogue: bias, LayerNorm over 256 cols, gamma/beta, ReLU
  float bcol[8], gc[8], bc[8];
#pragma unroll
  for (int t = 0; t < 8; ++t) {
    int col = t * 32 + l31;
    bcol[t] = h_bias[col];
    gc[t] = gamma[col];
    bc[t] = beta[col];
  }
#pragma unroll
  for (int t = 0; t < 8; ++t)
#pragma unroll
    for (int r = 0; r < 16; ++r) acc[t][r] += bcol[t];

  const int m_base = m0 + wave * 32;
#pragma unroll
  for (int r = 0; r < 16; ++r) {
    float s = 0.f, q = 0.f;
#pragma unroll
    for (int t = 0; t < 8; ++t) { float v = acc[t][r]; s += v; q += v * v; }
#pragma unroll
    for (int m = 16; m >= 1; m >>= 1) {
      s += __shfl_xor(s, m);
      q += __shfl_xor(q, m);
    }
    float mean = s * (1.0f / 256.0f);
    float var = q * (1.0f / 256.0f) - mean * mean;
    float rstd = rsqrtf(var + 1e-5f);
    int row = (r & 3) + ((r >> 2) << 3) + (half << 2);  // C/D layout, 32x32
    int grow = m_base + row;
    if (grow < NN) {
#pragma unroll
      for (int t = 0; t < 8; ++t) {
        float v = (acc[t][r] - mean) * rstd * gc[t] + bc[t];
        out[(size_t)grow * 256 + t * 32 + l31] = fmaxf(v, 0.0f);
      }
    }
  }
}

extern "C" void kernel_launch(void* const* d_in, const int* in_sizes, int n_in,
                              void* d_out, int out_size, void* d_ws, size_t ws_size,
                              hipStream_t stream) {
  const float* x      = (const float*)d_in[0];
  const int*   src    = (const int*)d_in[1];
  const int*   dst    = (const int*)d_in[2];
  const float* bases  = (const float*)d_in[3];
  const float* w_comp = (const float*)d_in[4];
  const float* loop_w = (const float*)d_in[5];
  const float* h_bias = (const float*)d_in[6];
  const float* gamma  = (const float*)d_in[7];
  const float* beta   = (const float*)d_in[8];
  float* out = (float*)d_out;

  char* ws = (char*)d_ws;
  unsigned short* Cp    = (unsigned short*)ws;                // 102,400,000 B
  unsigned short* Xbf   = (unsigned short*)(ws + 102400000);  //  51,200,000 B
  unsigned short* Bfrag = (unsigned short*)(ws + 153600000);  //     393,216 B
  int* rec = (int*)(ws + 153993216);                          //   6,400,000 B (N x 64B lines)
  int* ovf = (int*)(ws + 160393216);                          //   6,400,000 B
  // total 166,793,216 B

  hipMemsetAsync(rec, 0, 6400000, stream);

  prep<<<16393, 256, 0, stream>>>(x, bases, loop_w, src, dst, Xbf, Bfrag, rec, ovf);
  agg_edges<<<12500, 256, 0, stream>>>(rec, ovf, w_comp, Xbf, Cp);
  gemm_ln<<<(NN + BM - 1) / BM, 256, 0, stream>>>(Cp, Xbf, Bfrag, h_bias, gamma, beta, out);
}